// Round 3
// baseline (1832.069 us; speedup 1.0000x reference)
//
#include <hip/hip_runtime.h>

#define NUM_CENTERS 256
#define CAPACITY    2048
#define FEAT_DIM    768
#define BATCH       65536
#define VEC_PER_ROW (FEAT_DIM / 4)   // 192 float4 per row (3072 B)

// Native clang vector type: the nontemporal builtins require it.
typedef float f32x4 __attribute__((ext_vector_type(4)));

// One block (192 threads = 3 waves) per sample — the shallowest possible
// dependency graph:
//   s_load c,r (blockIdx-uniform -> scalar cache)
//   -> one global_load_dwordx4 per lane (3 x 1KB wave-instructions per row)
//   -> one nontemporal store per lane.
// No loop, no register pressure, 10 blocks/CU resident, block-level
// parallelism (65536 independent blocks) hides the index->data latency chain.
// Both streams are touch-once -> nontemporal on both sides keeps the 1.6 GB
// bank and 201 MB output from thrashing L2/L3.
__global__ __launch_bounds__(VEC_PER_ROW) void gather_rows_kernel(
        const f32x4* __restrict__ bank,
        const int*   __restrict__ center_ids,
        const int*   __restrict__ rand_idx,
        f32x4*       __restrict__ out) {
    const int s = blockIdx.x;
    const int c = center_ids[s];   // block-uniform -> s_load_dword
    const int r = rand_idx[s];

    // 64-bit offsets: bank spans 1.6 GB (402M float4 elements).
    const long long src_off = ((long long)c * CAPACITY + r) * (long long)VEC_PER_ROW;
    const long long dst_off = (long long)s * (long long)VEC_PER_ROW;

    const f32x4 v = __builtin_nontemporal_load(&bank[src_off + threadIdx.x]);
    __builtin_nontemporal_store(v, &out[dst_off + threadIdx.x]);
}

extern "C" void kernel_launch(void* const* d_in, const int* in_sizes, int n_in,
                              void* d_out, int out_size, void* d_ws, size_t ws_size,
                              hipStream_t stream) {
    const f32x4* bank       = (const f32x4*)d_in[0];
    const int*   center_ids = (const int*)d_in[1];
    const int*   rand_idx   = (const int*)d_in[2];
    f32x4*       out        = (f32x4*)d_out;

    // Problem shape is static (BATCH=65536). Do NOT derive the grid from
    // in_sizes: its unit semantics (bytes vs elements) previously caused a
    // 4x-oversized grid whose OOB writes corrupted neighboring buffers and
    // made graph replays diverge.
    gather_rows_kernel<<<BATCH, VEC_PER_ROW, 0, stream>>>(bank, center_ids, rand_idx, out);
}

// Round 4
// 1787.815 us; speedup vs baseline: 1.0248x; 1.0248x over previous
//
#include <hip/hip_runtime.h>

#define NUM_CENTERS 256
#define CAPACITY    2048
#define FEAT_DIM    768
#define BATCH       65536
#define VEC_PER_ROW (FEAT_DIM / 4)   // 192 float4 per row (3072 B)

typedef float f32x4 __attribute__((ext_vector_type(4)));

// One block (192 threads = 3 waves) per sample — shallowest dependency graph:
//   s_load c,r (blockIdx-uniform -> scalar cache)
//   -> one global_load_dwordx4 per lane (3 x 1KB wave-instructions per row)
//   -> one global_store_dwordx4 per lane.
// NO nontemporal hints: the distinct read set (~190 MB) and the output
// (201 MB) each fit in the 256 MB L3. Normal stores retire into L3 (writeback
// deferred), normal loads allocate for replay reuse. Measured: NT hints cost
// ~30-50 us here (R2: NT-store 1816, R3: NT-both 1832, plain 1783.7).
__global__ __launch_bounds__(VEC_PER_ROW) void gather_rows_kernel(
        const f32x4* __restrict__ bank,
        const int*   __restrict__ center_ids,
        const int*   __restrict__ rand_idx,
        f32x4*       __restrict__ out) {
    const int s = blockIdx.x;
    const int c = center_ids[s];   // block-uniform -> s_load_dword
    const int r = rand_idx[s];

    // 64-bit offsets: bank spans 1.6 GB (402M float4 elements).
    const long long src_off = ((long long)c * CAPACITY + r) * (long long)VEC_PER_ROW;
    const long long dst_off = (long long)s * (long long)VEC_PER_ROW;

    out[dst_off + threadIdx.x] = bank[src_off + threadIdx.x];
}

extern "C" void kernel_launch(void* const* d_in, const int* in_sizes, int n_in,
                              void* d_out, int out_size, void* d_ws, size_t ws_size,
                              hipStream_t stream) {
    const f32x4* bank       = (const f32x4*)d_in[0];
    const int*   center_ids = (const int*)d_in[1];
    const int*   rand_idx   = (const int*)d_in[2];
    f32x4*       out        = (f32x4*)d_out;

    // Problem shape is static (BATCH=65536). Do NOT derive the grid from
    // in_sizes: its unit semantics (bytes vs elements) previously caused a
    // 4x-oversized grid whose OOB writes corrupted neighboring buffers and
    // made graph replays diverge.
    gather_rows_kernel<<<BATCH, VEC_PER_ROW, 0, stream>>>(bank, center_ids, rand_idx, out);
}